// Round 19
// baseline (122.381 us; speedup 1.0000x reference)
//
#include <hip/hip_runtime.h>
#include <hip/hip_bf16.h>
#include <stdint.h>

// LatticeCharCell: B=4096, M=16, IN=512, H=512
// R19 pipeline (4 dispatches) = R17 base, latg rebuilt as pure-DMA GEMM:
//   k_cvt_all: bf16 XH=[input|h0], Wcat, Wlc (one dispatch)
//   k_gemm0  : C1u = bf16(XH @ Wcat^T) (4096x2048), 128^2 tile (13us control)
//   k_latg   : lc = bf16(all_c @ Wlc^T), 256^2 tile, 8 waves, BK=32.
//              A staged as RAW F32 via global_load_lds (no reg round-trip,
//              no cvt kernel); f32->bf16 convert at fragment-read time.
//              B bf16 via gload_lds. LDS 96KB. XOR slot swizzle (2-way, free).
//              Predicated lc store (m<nw).
//   k_epi    : lattice softmax-cell math at full occupancy, coalesced reads.

typedef __attribute__((ext_vector_type(8))) short short8;
typedef __attribute__((ext_vector_type(4))) float f32x4;
typedef __attribute__((ext_vector_type(4))) unsigned short us4;

__device__ __forceinline__ unsigned short f2bf(float f) {
  union { float f; unsigned u; } v; v.f = f;
  return (unsigned short)((v.u + 0x7fffu + ((v.u >> 16) & 1u)) >> 16);
}
__device__ __forceinline__ unsigned short f2bf_h(float f) {
  __hip_bfloat16 h = __float2bfloat16(f);   // pairs into v_cvt_pk_bf16_f32
  return *reinterpret_cast<unsigned short*>(&h);
}
__device__ __forceinline__ float bf2f(unsigned short u) {
  return __uint_as_float((unsigned)u << 16);
}
__device__ __forceinline__ float sigmoidf_(float x) {
  return 1.f / (1.f + __expf(-x));
}
__device__ __forceinline__ float fast_tanh(float x) {
  float e = __expf(-2.f * fmaxf(x, -30.f));
  return (1.f - e) / (1.f + e);
}

// ---------------- merged conversion kernel ----------------
__global__ void k_cvt_all(const float* __restrict__ x, const float* __restrict__ h,
                          const float* __restrict__ Wii, const float* __restrict__ Wig,
                          const float* __restrict__ Wio, const float* __restrict__ Wlx,
                          const float* __restrict__ Whi, const float* __restrict__ Whg,
                          const float* __restrict__ Who, const float* __restrict__ Wlcf,
                          unsigned short* __restrict__ XH, unsigned short* __restrict__ Wcat,
                          unsigned short* __restrict__ Wlc) {
  const int bb = blockIdx.x;
  const int tid = threadIdx.x;
  us4 o;
  if (bb < 4096) {                     // XH = [input | h0]
    const int t = bb * 256 + tid;
    const int b = t >> 8;
    const int col = (t & 255) * 4;
    const float* src = (col < 512) ? (x + (size_t)b * 512 + col)
                                   : (h + (size_t)b * 512 + (col - 512));
    f32x4 v = *(const f32x4*)src;
    o[0] = f2bf(v[0]); o[1] = f2bf(v[1]); o[2] = f2bf(v[2]); o[3] = f2bf(v[3]);
    *(us4*)(XH + (size_t)t * 4) = o;
  } else if (bb < 6144) {              // Wcat
    const int t = (bb - 4096) * 256 + tid;
    const int row = t >> 8;
    const int col = (t & 255) * 4;
    const int sec = row >> 9, r = row & 511;
    if (col < 512) {
      const float* W = sec == 0 ? Wii : sec == 1 ? Wig : sec == 2 ? Wio : Wlx;
      f32x4 v = *(const f32x4*)(W + (size_t)r * 512 + col);
      o[0] = f2bf(v[0]); o[1] = f2bf(v[1]); o[2] = f2bf(v[2]); o[3] = f2bf(v[3]);
    } else if (sec < 3) {
      const float* W = sec == 0 ? Whi : sec == 1 ? Whg : Who;
      f32x4 v = *(const f32x4*)(W + (size_t)r * 512 + (col - 512));
      o[0] = f2bf(v[0]); o[1] = f2bf(v[1]); o[2] = f2bf(v[2]); o[3] = f2bf(v[3]);
    } else {
      o[0] = 0; o[1] = 0; o[2] = 0; o[3] = 0;
    }
    *(us4*)(Wcat + (size_t)t * 4) = o;
  } else {                             // Wlc
    const int t = (bb - 6144) * 256 + tid;
    f32x4 v = *(const f32x4*)(Wlcf + (size_t)t * 4);
    o[0] = f2bf(v[0]); o[1] = f2bf(v[1]); o[2] = f2bf(v[2]); o[3] = f2bf(v[3]);
    *(us4*)(Wlc + (size_t)t * 4) = o;
  }
}

// ---------------- gate GEMM (C1u = bf16(XH @ Wcat^T)), 128^2 tile ----------------
__global__ __launch_bounds__(256) void k_gemm0(
    const unsigned short* __restrict__ A, const unsigned short* __restrict__ Bm,
    unsigned short* __restrict__ C, int Ndim, int Kdim, int nbx) {
  __shared__ unsigned short As[2][128 * 64];
  __shared__ unsigned short Bs[2][128 * 64];
  const int tid = threadIdx.x;
  const int lane = tid & 63, wid = tid >> 6;
  const int wr = wid >> 1, wc = wid & 1;
  const int l15 = lane & 15, lhi = lane >> 4;

  const int chunk = gridDim.x >> 3;
  const int bid = (blockIdx.x & 7) * chunk + (blockIdx.x >> 3);
  const int brow = bid / nbx, bcol = bid % nbx;
  const int m0 = brow * 128, n0 = bcol * 128;

  f32x4 acc[4][4];
#pragma unroll
  for (int i = 0; i < 4; ++i)
#pragma unroll
    for (int j = 0; j < 4; ++j) acc[i][j] = (f32x4){0.f, 0.f, 0.f, 0.f};

  const int cb0 = wid * 64;
  auto stage = [&](int buf, int k0) {
#pragma unroll
    for (int q = 0; q < 4; ++q) {
      const int cb = q * 256 + cb0;
      const int chunkid = cb + lane;
      const int row = chunkid >> 3, slot = chunkid & 7;
      const int kk = k0 + ((slot ^ (row & 7)) << 3);
      __builtin_amdgcn_global_load_lds(
          (const __attribute__((address_space(1))) unsigned int*)(A + (size_t)(m0 + row) * Kdim + kk),
          (__attribute__((address_space(3))) unsigned int*)(As[buf] + cb * 8), 16, 0, 0);
      __builtin_amdgcn_global_load_lds(
          (const __attribute__((address_space(1))) unsigned int*)(Bm + (size_t)(n0 + row) * Kdim + kk),
          (__attribute__((address_space(3))) unsigned int*)(Bs[buf] + cb * 8), 16, 0, 0);
    }
  };

  const int nt = Kdim >> 6;
  stage(0, 0);
  __syncthreads();

  const int swz = (lane & 7) << 4;
  for (int t = 0; t < nt; ++t) {
    const int cur = t & 1;
    if (t + 1 < nt) stage(cur ^ 1, (t + 1) << 6);
    const char* Ab = (const char*)As[cur];
    const char* Bb = (const char*)Bs[cur];
#pragma unroll
    for (int s = 0; s < 2; ++s) {
      short8 av[4], bv[4];
#pragma unroll
      for (int mi = 0; mi < 4; ++mi) {
        const int row = wr * 64 + mi * 16 + l15;
        av[mi] = *(const short8*)(Ab + row * 128 + ((s * 64 + lhi * 16) ^ swz));
      }
#pragma unroll
      for (int ni = 0; ni < 4; ++ni) {
        const int row = wc * 64 + ni * 16 + l15;
        bv[ni] = *(const short8*)(Bb + row * 128 + ((s * 64 + lhi * 16) ^ swz));
      }
#pragma unroll
      for (int mi = 0; mi < 4; ++mi)
#pragma unroll
        for (int ni = 0; ni < 4; ++ni)
          acc[mi][ni] = __builtin_amdgcn_mfma_f32_16x16x32_bf16(av[mi], bv[ni], acc[mi][ni], 0, 0, 0);
    }
    __syncthreads();
  }

#pragma unroll
  for (int mi = 0; mi < 4; ++mi) {
    const int gr = m0 + wr * 64 + mi * 16 + lhi * 4;
#pragma unroll
    for (int ni = 0; ni < 4; ++ni) {
      const int gc = n0 + wc * 64 + ni * 16 + l15;
#pragma unroll
      for (int j = 0; j < 4; ++j)
        C[(size_t)(gr + j) * Ndim + gc] = f2bf(acc[mi][ni][j]);
    }
  }
}

// ---------------- pure lattice GEMM: lc = bf16(all_c @ Wlc^T) ----------------
// 256x256 tile, 8 waves (2x4), BK=32. A staged RAW F32 via gload_lds into
// [2][256 rows x 8 slots x 16B] with slot^(row&7) swizzle (inverse on global
// source); f32->bf16 convert at fragment read. B bf16 pair-row scheme (R17).
// LDS 96KB; one barrier per k-step (gemm0-identical loop).
__global__ __launch_bounds__(512) void k_latg(
    const float* __restrict__ Af,           // all_c f32 [65536 x 512]
    const unsigned short* __restrict__ Bm,  // Wlc bf16 [512 x 512]
    const int* __restrict__ num_word,
    unsigned short* __restrict__ lcb) {     // lc bf16 [65536 x 512]
  __shared__ float As[2][256 * 32];            // 32KB each (f32)
  __shared__ unsigned short Bs[2][256 * 32];   // 16KB each (bf16)
  const int tid = threadIdx.x;
  const int lane = tid & 63, wid = tid >> 6;
  const int wrow = wid >> 2, wcol = wid & 3;
  const int l15 = lane & 15, lhi = lane >> 4;

  const int chunk = gridDim.x >> 3;             // grid 512 -> 64
  const int bid = (blockIdx.x & 7) * chunk + (blockIdx.x >> 3);
  const int brow = bid >> 1, bcol = bid & 1;
  const int m0 = brow * 256, n0 = bcol * 256;

  f32x4 acc[8][4];
#pragma unroll
  for (int i = 0; i < 8; ++i)
#pragma unroll
    for (int j = 0; j < 4; ++j) acc[i][j] = (f32x4){0.f, 0.f, 0.f, 0.f};

  // A: 2048 chunks of 16B (4 f32); chunk c: row=c>>3, phys slot=c&7,
  // logical slot gi = phys ^ (row&7); global k = k0 + gi*4 (f32).
  auto stageA = [&](int buf, int k0) {
#pragma unroll
    for (int q = 0; q < 4; ++q) {
      const int cb = q * 512 + wid * 64;        // wave-uniform chunk base
      const int c = cb + lane;
      const int row = c >> 3, phys = c & 7;
      const int gi = phys ^ (row & 7);
      const int kk = k0 + gi * 4;
      __builtin_amdgcn_global_load_lds(
          (const __attribute__((address_space(1))) unsigned int*)(Af + (size_t)(m0 + row) * 512 + kk),
          (__attribute__((address_space(3))) unsigned int*)(As[buf] + cb * 4), 16, 0, 0);
    }
  };
  // B: pair-row scheme (R17-proven, 0 conflicts)
  auto stageB = [&](int buf, int k0) {
#pragma unroll
    for (int q = 0; q < 2; ++q) {
      const int cb = q * 512 + wid * 64;
      const int c = cb + lane;
      const int pr = c >> 3, phys = c & 7;
      const int gi = phys ^ (pr & 7);
      const int row = pr * 2 + (gi >> 2);
      const int kk = k0 + ((gi & 3) << 3);
      __builtin_amdgcn_global_load_lds(
          (const __attribute__((address_space(1))) unsigned int*)(Bm + (size_t)(n0 + row) * 512 + kk),
          (__attribute__((address_space(3))) unsigned int*)(Bs[buf] + cb * 8), 16, 0, 0);
    }
  };

  auto compute = [&](int buf) {
    const char* Ab = (const char*)As[buf];
    const char* Bb = (const char*)Bs[buf];
    short8 av[8];
    short8 bv[4];
#pragma unroll
    for (int mi = 0; mi < 8; ++mi) {
      const int row = wrow * 128 + mi * 16 + l15;
      const int s0 = (2 * lhi) ^ (row & 7);
      const int s1 = (2 * lhi + 1) ^ (row & 7);
      const f32x4 a0 = *(const f32x4*)(Ab + row * 128 + s0 * 16);
      const f32x4 a1 = *(const f32x4*)(Ab + row * 128 + s1 * 16);
      av[mi][0] = (short)f2bf_h(a0[0]); av[mi][1] = (short)f2bf_h(a0[1]);
      av[mi][2] = (short)f2bf_h(a0[2]); av[mi][3] = (short)f2bf_h(a0[3]);
      av[mi][4] = (short)f2bf_h(a1[0]); av[mi][5] = (short)f2bf_h(a1[1]);
      av[mi][6] = (short)f2bf_h(a1[2]); av[mi][7] = (short)f2bf_h(a1[3]);
    }
#pragma unroll
    for (int ni = 0; ni < 4; ++ni) {
      const int row = wcol * 64 + ni * 16 + l15;
      const int pr = row >> 1;
      bv[ni] = *(const short8*)(Bb + pr * 128 +
                (((lhi + ((row & 1) << 2)) ^ (pr & 7)) << 4));
    }
#pragma unroll
    for (int mi = 0; mi < 8; ++mi)
#pragma unroll
      for (int ni = 0; ni < 4; ++ni)
        acc[mi][ni] = __builtin_amdgcn_mfma_f32_16x16x32_bf16(av[mi], bv[ni], acc[mi][ni], 0, 0, 0);
  };

  stageA(0, 0);
  stageB(0, 0);
  __syncthreads();

#pragma unroll 1
  for (int t = 0; t < 16; ++t) {
    const int cur = t & 1;
    if (t + 1 < 16) {
      stageA(cur ^ 1, (t + 1) << 5);
      stageB(cur ^ 1, (t + 1) << 5);
    }
    compute(cur);
    __syncthreads();
  }

  // store lc (bf16), predicated on m < num_word[b] (rows m>=nw never read)
#pragma unroll
  for (int mi = 0; mi < 8; ++mi) {
    const int rbase = m0 + wrow * 128 + mi * 16;
    const int nw = num_word[rbase >> 4];
    const int gr = rbase + lhi * 4;
#pragma unroll
    for (int ni = 0; ni < 4; ++ni) {
      const int gc = n0 + wcol * 64 + ni * 16 + l15;
#pragma unroll
      for (int j = 0; j < 4; ++j)
        if (lhi * 4 + j < nw)
          lcb[(size_t)(gr + j) * 512 + gc] = f2bf(acc[mi][ni][j]);
    }
  }
}

// ---------------- lattice epilogue (full occupancy, coalesced) ----------------
__global__ __launch_bounds__(512) void k_epi(
    const unsigned short* __restrict__ lc,   // [65536 x 512] bf16
    const float* __restrict__ all_c,         // [4096 x 16 x 512] f32
    const unsigned short* __restrict__ C1u,  // [4096 x 2048] bf16
    const int* __restrict__ num_word,
    const float* __restrict__ b_ii, const float* __restrict__ b_hi,
    const float* __restrict__ b_ig, const float* __restrict__ b_hg,
    const float* __restrict__ b_io, const float* __restrict__ b_ho,
    const float* __restrict__ b_lx, const float* __restrict__ b_lc,
    float* __restrict__ outH, float* __restrict__ outC) {
  const int b = blockIdx.x;
  const int hc = threadIdx.x;
  const int nw = num_word[b];                 // uniform per block
  const size_t base = (size_t)b * 2048;

  const float pre = bf2f(C1u[base + 1536 + hc]) + b_lx[hc] + b_lc[hc];
  const unsigned short* lcp = lc + ((size_t)b * 16) * 512 + hc;
  const float* wp = all_c + ((size_t)b * 16) * 512 + hc;

  float se = 0.f, sew = 0.f;
#pragma unroll 4
  for (int m = 0; m < nw; ++m) {              // wave-uniform trip count
    const float ib = sigmoidf_(pre + bf2f(lcp[(size_t)m * 512]));
    const float e = __expf(ib);
    se += e;
    sew += e * wp[(size_t)m * 512];
  }

  const float ig = sigmoidf_(bf2f(C1u[base + hc]) + b_ii[hc] + b_hi[hc]);
  const float g  = fast_tanh(bf2f(C1u[base + 512 + hc]) + b_ig[hc] + b_hg[hc]);
  const float og = sigmoidf_(bf2f(C1u[base + 1024 + hc]) + b_io[hc] + b_ho[hc]);
  const float ei = __expf(ig);
  const float denom = ei + se;                // nw==0 -> denom=ei, c=g
  const float cc = (sew + ei * g) / denom;
  outH[(size_t)b * 512 + hc] = og * fast_tanh(cc);
  outC[(size_t)b * 512 + hc] = cc;
}

extern "C" void kernel_launch(void* const* d_in, const int* in_sizes, int n_in,
                              void* d_out, int out_size, void* d_ws, size_t ws_size,
                              hipStream_t stream) {
  const float* input    = (const float*)d_in[0];
  const float* h0       = (const float*)d_in[1];
  const float* all_c    = (const float*)d_in[3];
  const int*   num_word = (const int*)d_in[4];
  const float* W_ii = (const float*)d_in[5];  const float* b_ii = (const float*)d_in[6];
  const float* W_hi = (const float*)d_in[7];  const float* b_hi = (const float*)d_in[8];
  const float* W_ig = (const float*)d_in[13]; const float* b_ig = (const float*)d_in[14];
  const float* W_hg = (const float*)d_in[15]; const float* b_hg = (const float*)d_in[16];
  const float* W_io = (const float*)d_in[17]; const float* b_io = (const float*)d_in[18];
  const float* W_ho = (const float*)d_in[19]; const float* b_ho = (const float*)d_in[20];
  const float* W_lx = (const float*)d_in[21]; const float* b_lx = (const float*)d_in[22];
  const float* W_lc = (const float*)d_in[23]; const float* b_lc = (const float*)d_in[24];

  char* ws = (char*)d_ws;
  unsigned short* XH   = (unsigned short*)(ws);               // 8 MB
  unsigned short* Wcat = (unsigned short*)(ws + 8388608);     // 4 MB
  unsigned short* Wlc  = (unsigned short*)(ws + 12582912);    // 0.5 MB
  unsigned short* C1u  = (unsigned short*)(ws + 13107200);    // 16 MB (bf16)
  unsigned short* lc   = (unsigned short*)(ws + 29884416);    // 64 MB (bf16)

  float* outH = (float*)d_out;
  float* outC = outH + (size_t)4096 * 512;

  k_cvt_all<<<6400, 256, 0, stream>>>(input, h0, W_ii, W_ig, W_io, W_lx,
                                      W_hi, W_hg, W_ho, W_lc, XH, Wcat, Wlc);

  // C1u = bf16(XH @ Wcat^T) : M=4096, N=2048, K=1024 -> grid 512
  k_gemm0<<<512, 256, 0, stream>>>(XH, Wcat, C1u, 2048, 1024, 16);

  // lc = bf16(all_c @ Wlc^T) : M=65536, N=512 (256^2 tile, BK=32) -> grid 512
  k_latg<<<512, 512, 0, stream>>>(all_c, Wlc, num_word, lc);

  // lattice cell epilogue: one block per batch, one thread per hc
  k_epi<<<4096, 512, 0, stream>>>(lc, all_c, C1u, num_word,
      b_ii, b_hi, b_ig, b_hg, b_io, b_ho, b_lx, b_lc, outH, outC);
}

// Round 20
// 111.340 us; speedup vs baseline: 1.0992x; 1.0992x over previous
//
#include <hip/hip_runtime.h>
#include <hip/hip_bf16.h>
#include <stdint.h>

// LatticeCharCell: B=4096, M=16, IN=512, H=512
// R20 = R17 verbatim (session best, 112.5us). R18 (unroll) and R19 (pure-DMA
// f32 A) both regressed; this is the measured-optimal configuration:
//   k_cvt_all: bf16 XH=[input|h0], Wcat, Wlc (one dispatch)
//   k_gemm0  : C1u = bf16(XH @ Wcat^T) (4096x2048), 128^2 tile
//   k_latg   : lc = bf16(all_c @ Wlc^T), 256^2 tile, 8 waves, BK=32, 64KB LDS,
//              A reg-staged 2-deep (SA/SB), B via gload_lds, pair-row swizzle
//              (0 bank conflicts), predicated lc store (m<nw), setprio in
//              compute cluster (kept from R17's measured config).
//   k_epi    : lattice softmax-cell math at full occupancy, coalesced reads.

typedef __attribute__((ext_vector_type(8))) short short8;
typedef __attribute__((ext_vector_type(4))) float f32x4;
typedef __attribute__((ext_vector_type(4))) unsigned short us4;

__device__ __forceinline__ unsigned short f2bf(float f) {
  union { float f; unsigned u; } v; v.f = f;
  return (unsigned short)((v.u + 0x7fffu + ((v.u >> 16) & 1u)) >> 16);
}
__device__ __forceinline__ unsigned short f2bf_h(float f) {
  __hip_bfloat16 h = __float2bfloat16(f);   // pairs into v_cvt_pk_bf16_f32
  return *reinterpret_cast<unsigned short*>(&h);
}
__device__ __forceinline__ float bf2f(unsigned short u) {
  return __uint_as_float((unsigned)u << 16);
}
__device__ __forceinline__ float sigmoidf_(float x) {
  return 1.f / (1.f + __expf(-x));
}
__device__ __forceinline__ float fast_tanh(float x) {
  float e = __expf(-2.f * fmaxf(x, -30.f));
  return (1.f - e) / (1.f + e);
}

// ---------------- merged conversion kernel ----------------
__global__ void k_cvt_all(const float* __restrict__ x, const float* __restrict__ h,
                          const float* __restrict__ Wii, const float* __restrict__ Wig,
                          const float* __restrict__ Wio, const float* __restrict__ Wlx,
                          const float* __restrict__ Whi, const float* __restrict__ Whg,
                          const float* __restrict__ Who, const float* __restrict__ Wlcf,
                          unsigned short* __restrict__ XH, unsigned short* __restrict__ Wcat,
                          unsigned short* __restrict__ Wlc) {
  const int bb = blockIdx.x;
  const int tid = threadIdx.x;
  us4 o;
  if (bb < 4096) {                     // XH = [input | h0]
    const int t = bb * 256 + tid;
    const int b = t >> 8;
    const int col = (t & 255) * 4;
    const float* src = (col < 512) ? (x + (size_t)b * 512 + col)
                                   : (h + (size_t)b * 512 + (col - 512));
    f32x4 v = *(const f32x4*)src;
    o[0] = f2bf(v[0]); o[1] = f2bf(v[1]); o[2] = f2bf(v[2]); o[3] = f2bf(v[3]);
    *(us4*)(XH + (size_t)t * 4) = o;
  } else if (bb < 6144) {              // Wcat
    const int t = (bb - 4096) * 256 + tid;
    const int row = t >> 8;
    const int col = (t & 255) * 4;
    const int sec = row >> 9, r = row & 511;
    if (col < 512) {
      const float* W = sec == 0 ? Wii : sec == 1 ? Wig : sec == 2 ? Wio : Wlx;
      f32x4 v = *(const f32x4*)(W + (size_t)r * 512 + col);
      o[0] = f2bf(v[0]); o[1] = f2bf(v[1]); o[2] = f2bf(v[2]); o[3] = f2bf(v[3]);
    } else if (sec < 3) {
      const float* W = sec == 0 ? Whi : sec == 1 ? Whg : Who;
      f32x4 v = *(const f32x4*)(W + (size_t)r * 512 + (col - 512));
      o[0] = f2bf(v[0]); o[1] = f2bf(v[1]); o[2] = f2bf(v[2]); o[3] = f2bf(v[3]);
    } else {
      o[0] = 0; o[1] = 0; o[2] = 0; o[3] = 0;
    }
    *(us4*)(Wcat + (size_t)t * 4) = o;
  } else {                             // Wlc
    const int t = (bb - 6144) * 256 + tid;
    f32x4 v = *(const f32x4*)(Wlcf + (size_t)t * 4);
    o[0] = f2bf(v[0]); o[1] = f2bf(v[1]); o[2] = f2bf(v[2]); o[3] = f2bf(v[3]);
    *(us4*)(Wlc + (size_t)t * 4) = o;
  }
}

// ---------------- gate GEMM (C1u = bf16(XH @ Wcat^T)), 128^2 tile ----------------
__global__ __launch_bounds__(256) void k_gemm0(
    const unsigned short* __restrict__ A, const unsigned short* __restrict__ Bm,
    unsigned short* __restrict__ C, int Ndim, int Kdim, int nbx) {
  __shared__ unsigned short As[2][128 * 64];
  __shared__ unsigned short Bs[2][128 * 64];
  const int tid = threadIdx.x;
  const int lane = tid & 63, wid = tid >> 6;
  const int wr = wid >> 1, wc = wid & 1;
  const int l15 = lane & 15, lhi = lane >> 4;

  const int chunk = gridDim.x >> 3;
  const int bid = (blockIdx.x & 7) * chunk + (blockIdx.x >> 3);
  const int brow = bid / nbx, bcol = bid % nbx;
  const int m0 = brow * 128, n0 = bcol * 128;

  f32x4 acc[4][4];
#pragma unroll
  for (int i = 0; i < 4; ++i)
#pragma unroll
    for (int j = 0; j < 4; ++j) acc[i][j] = (f32x4){0.f, 0.f, 0.f, 0.f};

  const int cb0 = wid * 64;
  auto stage = [&](int buf, int k0) {
#pragma unroll
    for (int q = 0; q < 4; ++q) {
      const int cb = q * 256 + cb0;
      const int chunkid = cb + lane;
      const int row = chunkid >> 3, slot = chunkid & 7;
      const int kk = k0 + ((slot ^ (row & 7)) << 3);
      __builtin_amdgcn_global_load_lds(
          (const __attribute__((address_space(1))) unsigned int*)(A + (size_t)(m0 + row) * Kdim + kk),
          (__attribute__((address_space(3))) unsigned int*)(As[buf] + cb * 8), 16, 0, 0);
      __builtin_amdgcn_global_load_lds(
          (const __attribute__((address_space(1))) unsigned int*)(Bm + (size_t)(n0 + row) * Kdim + kk),
          (__attribute__((address_space(3))) unsigned int*)(Bs[buf] + cb * 8), 16, 0, 0);
    }
  };

  const int nt = Kdim >> 6;
  stage(0, 0);
  __syncthreads();

  const int swz = (lane & 7) << 4;
  for (int t = 0; t < nt; ++t) {
    const int cur = t & 1;
    if (t + 1 < nt) stage(cur ^ 1, (t + 1) << 6);
    const char* Ab = (const char*)As[cur];
    const char* Bb = (const char*)Bs[cur];
#pragma unroll
    for (int s = 0; s < 2; ++s) {
      short8 av[4], bv[4];
#pragma unroll
      for (int mi = 0; mi < 4; ++mi) {
        const int row = wr * 64 + mi * 16 + l15;
        av[mi] = *(const short8*)(Ab + row * 128 + ((s * 64 + lhi * 16) ^ swz));
      }
#pragma unroll
      for (int ni = 0; ni < 4; ++ni) {
        const int row = wc * 64 + ni * 16 + l15;
        bv[ni] = *(const short8*)(Bb + row * 128 + ((s * 64 + lhi * 16) ^ swz));
      }
#pragma unroll
      for (int mi = 0; mi < 4; ++mi)
#pragma unroll
        for (int ni = 0; ni < 4; ++ni)
          acc[mi][ni] = __builtin_amdgcn_mfma_f32_16x16x32_bf16(av[mi], bv[ni], acc[mi][ni], 0, 0, 0);
    }
    __syncthreads();
  }

#pragma unroll
  for (int mi = 0; mi < 4; ++mi) {
    const int gr = m0 + wr * 64 + mi * 16 + lhi * 4;
#pragma unroll
    for (int ni = 0; ni < 4; ++ni) {
      const int gc = n0 + wc * 64 + ni * 16 + l15;
#pragma unroll
      for (int j = 0; j < 4; ++j)
        C[(size_t)(gr + j) * Ndim + gc] = f2bf(acc[mi][ni][j]);
    }
  }
}

// ---------------- pure lattice GEMM: lc = bf16(all_c @ Wlc^T) ----------------
// 256x256 tile, 8 waves (2x4), BK=32, 64KB LDS (2 blocks/CU).
// A reg-staged 2-deep (SA/SB); B via gload_lds; pair-row swizzle (0 conflicts).
__global__ __launch_bounds__(512) void k_latg(
    const float* __restrict__ Af,           // all_c f32 [65536 x 512]
    const unsigned short* __restrict__ Bm,  // Wlc bf16 [512 x 512]
    const int* __restrict__ num_word,
    unsigned short* __restrict__ lcb) {     // lc bf16 [65536 x 512]
  __shared__ unsigned short As[2][256 * 32];   // 16KB each
  __shared__ unsigned short Bs[2][256 * 32];
  const int tid = threadIdx.x;
  const int lane = tid & 63, wid = tid >> 6;
  const int wrow = wid >> 2, wcol = wid & 3;
  const int l15 = lane & 15, lhi = lane >> 4;

  const int chunk = gridDim.x >> 3;             // grid 512 -> 64
  const int bid = (blockIdx.x & 7) * chunk + (blockIdx.x >> 3);
  const int brow = bid >> 1, bcol = bid & 1;
  const int m0 = brow * 256, n0 = bcol * 256;

  f32x4 acc[8][4];
#pragma unroll
  for (int i = 0; i < 8; ++i)
#pragma unroll
    for (int j = 0; j < 4; ++j) acc[i][j] = (f32x4){0.f, 0.f, 0.f, 0.f};

  f32x4 SA[2][2], SB[2][2];                     // two in-flight A sets (static idx)

  auto loadA = [&](f32x4 (&dst)[2][2], int k0) {
#pragma unroll
    for (int q = 0; q < 2; ++q) {
      const int c = q * 512 + tid;
      const int row = c >> 2, s = c & 3;
      const float* p = Af + (size_t)(m0 + row) * 512 + k0 + s * 8;
      dst[q][0] = *(const f32x4*)p;
      dst[q][1] = *(const f32x4*)(p + 4);
    }
  };
  auto writeA = [&](int buf, f32x4 (&src)[2][2]) {
#pragma unroll
    for (int q = 0; q < 2; ++q) {
      const int c = q * 512 + tid;
      const int row = c >> 2, s = c & 3;
      const int pr = row >> 1;
      const int phys = (s + ((row & 1) << 2)) ^ (pr & 7);
      short8 v;
      v[0] = (short)f2bf_h(src[q][0][0]); v[1] = (short)f2bf_h(src[q][0][1]);
      v[2] = (short)f2bf_h(src[q][0][2]); v[3] = (short)f2bf_h(src[q][0][3]);
      v[4] = (short)f2bf_h(src[q][1][0]); v[5] = (short)f2bf_h(src[q][1][1]);
      v[6] = (short)f2bf_h(src[q][1][2]); v[7] = (short)f2bf_h(src[q][1][3]);
      *(short8*)((char*)As[buf] + pr * 128 + phys * 16) = v;
    }
  };
  auto stageB = [&](int buf, int k0) {
#pragma unroll
    for (int q = 0; q < 2; ++q) {
      const int cb = q * 512 + wid * 64;        // wave-uniform chunk base
      const int c = cb + lane;
      const int pr = c >> 3, phys = c & 7;
      const int gi = phys ^ (pr & 7);
      const int row = pr * 2 + (gi >> 2);
      const int kk = k0 + ((gi & 3) << 3);
      __builtin_amdgcn_global_load_lds(
          (const __attribute__((address_space(1))) unsigned int*)(Bm + (size_t)(n0 + row) * 512 + kk),
          (__attribute__((address_space(3))) unsigned int*)(Bs[buf] + cb * 8), 16, 0, 0);
    }
  };

  auto compute = [&](int buf) {
    const char* Ab = (const char*)As[buf];
    const char* Bb = (const char*)Bs[buf];
    short8 av[8], bv[4];
#pragma unroll
    for (int mi = 0; mi < 8; ++mi) {
      const int row = wrow * 128 + mi * 16 + l15;
      const int pr = row >> 1;
      av[mi] = *(const short8*)(Ab + pr * 128 +
                (((lhi + ((row & 1) << 2)) ^ (pr & 7)) << 4));
    }
#pragma unroll
    for (int ni = 0; ni < 4; ++ni) {
      const int row = wcol * 64 + ni * 16 + l15;
      const int pr = row >> 1;
      bv[ni] = *(const short8*)(Bb + pr * 128 +
                (((lhi + ((row & 1) << 2)) ^ (pr & 7)) << 4));
    }
    __builtin_amdgcn_s_setprio(1);
#pragma unroll
    for (int mi = 0; mi < 8; ++mi)
#pragma unroll
      for (int ni = 0; ni < 4; ++ni)
        acc[mi][ni] = __builtin_amdgcn_mfma_f32_16x16x32_bf16(av[mi], bv[ni], acc[mi][ni], 0, 0, 0);
    __builtin_amdgcn_s_setprio(0);
  };

  // prologue: SA=tile0, SB=tile1; write tile0 into buf0
  loadA(SA, 0);
  loadA(SB, 32);
  stageB(0, 0);
  writeA(0, SA);
  __syncthreads();

#pragma unroll 1
  for (int t = 0; t < 16; t += 2) {
    // even step t (cur=0): refill SA with tile t+2, write SB (tile t+1) -> buf1
    if (t + 2 < 16) loadA(SA, (t + 2) << 5);
    if (t + 1 < 16) stageB(1, (t + 1) << 5);
    compute(0);
    if (t + 1 < 16) writeA(1, SB);
    __syncthreads();
    // odd step t+1 (cur=1): refill SB with tile t+3, write SA (tile t+2) -> buf0
    if (t + 3 < 16) loadA(SB, (t + 3) << 5);
    if (t + 2 < 16) stageB(0, (t + 2) << 5);
    compute(1);
    if (t + 2 < 16) writeA(0, SA);
    __syncthreads();
  }

  // store lc (bf16), predicated on m < num_word[b] (rows m>=nw never read)
#pragma unroll
  for (int mi = 0; mi < 8; ++mi) {
    const int rbase = m0 + wrow * 128 + mi * 16;
    const int nw = num_word[rbase >> 4];
    const int gr = rbase + lhi * 4;
#pragma unroll
    for (int ni = 0; ni < 4; ++ni) {
      const int gc = n0 + wcol * 64 + ni * 16 + l15;
#pragma unroll
      for (int j = 0; j < 4; ++j)
        if (lhi * 4 + j < nw)
          lcb[(size_t)(gr + j) * 512 + gc] = f2bf(acc[mi][ni][j]);
    }
  }
}

// ---------------- lattice epilogue (full occupancy, coalesced) ----------------
__global__ __launch_bounds__(512) void k_epi(
    const unsigned short* __restrict__ lc,   // [65536 x 512] bf16
    const float* __restrict__ all_c,         // [4096 x 16 x 512] f32
    const unsigned short* __restrict__ C1u,  // [4096 x 2048] bf16
    const int* __restrict__ num_word,
    const float* __restrict__ b_ii, const float* __restrict__ b_hi,
    const float* __restrict__ b_ig, const float* __restrict__ b_hg,
    const float* __restrict__ b_io, const float* __restrict__ b_ho,
    const float* __restrict__ b_lx, const float* __restrict__ b_lc,
    float* __restrict__ outH, float* __restrict__ outC) {
  const int b = blockIdx.x;
  const int hc = threadIdx.x;
  const int nw = num_word[b];                 // uniform per block
  const size_t base = (size_t)b * 2048;

  const float pre = bf2f(C1u[base + 1536 + hc]) + b_lx[hc] + b_lc[hc];
  const unsigned short* lcp = lc + ((size_t)b * 16) * 512 + hc;
  const float* wp = all_c + ((size_t)b * 16) * 512 + hc;

  float se = 0.f, sew = 0.f;
#pragma unroll 4
  for (int m = 0; m < nw; ++m) {              // wave-uniform trip count
    const float ib = sigmoidf_(pre + bf2f(lcp[(size_t)m * 512]));
    const float e = __expf(ib);
    se += e;
    sew += e * wp[(size_t)m * 512];
  }

  const float ig = sigmoidf_(bf2f(C1u[base + hc]) + b_ii[hc] + b_hi[hc]);
  const float g  = fast_tanh(bf2f(C1u[base + 512 + hc]) + b_ig[hc] + b_hg[hc]);
  const float og = sigmoidf_(bf2f(C1u[base + 1024 + hc]) + b_io[hc] + b_ho[hc]);
  const float ei = __expf(ig);
  const float denom = ei + se;                // nw==0 -> denom=ei, c=g
  const float cc = (sew + ei * g) / denom;
  outH[(size_t)b * 512 + hc] = og * fast_tanh(cc);
  outC[(size_t)b * 512 + hc] = cc;
}

extern "C" void kernel_launch(void* const* d_in, const int* in_sizes, int n_in,
                              void* d_out, int out_size, void* d_ws, size_t ws_size,
                              hipStream_t stream) {
  const float* input    = (const float*)d_in[0];
  const float* h0       = (const float*)d_in[1];
  const float* all_c    = (const float*)d_in[3];
  const int*   num_word = (const int*)d_in[4];
  const float* W_ii = (const float*)d_in[5];  const float* b_ii = (const float*)d_in[6];
  const float* W_hi = (const float*)d_in[7];  const float* b_hi = (const float*)d_in[8];
  const float* W_ig = (const float*)d_in[13]; const float* b_ig = (const float*)d_in[14];
  const float* W_hg = (const float*)d_in[15]; const float* b_hg = (const float*)d_in[16];
  const float* W_io = (const float*)d_in[17]; const float* b_io = (const float*)d_in[18];
  const float* W_ho = (const float*)d_in[19]; const float* b_ho = (const float*)d_in[20];
  const float* W_lx = (const float*)d_in[21]; const float* b_lx = (const float*)d_in[22];
  const float* W_lc = (const float*)d_in[23]; const float* b_lc = (const float*)d_in[24];

  char* ws = (char*)d_ws;
  unsigned short* XH   = (unsigned short*)(ws);               // 8 MB
  unsigned short* Wcat = (unsigned short*)(ws + 8388608);     // 4 MB
  unsigned short* Wlc  = (unsigned short*)(ws + 12582912);    // 0.5 MB
  unsigned short* C1u  = (unsigned short*)(ws + 13107200);    // 16 MB (bf16)
  unsigned short* lc   = (unsigned short*)(ws + 29884416);    // 64 MB (bf16)

  float* outH = (float*)d_out;
  float* outC = outH + (size_t)4096 * 512;

  k_cvt_all<<<6400, 256, 0, stream>>>(input, h0, W_ii, W_ig, W_io, W_lx,
                                      W_hi, W_hg, W_ho, W_lc, XH, Wcat, Wlc);

  // C1u = bf16(XH @ Wcat^T) : M=4096, N=2048, K=1024 -> grid 512
  k_gemm0<<<512, 256, 0, stream>>>(XH, Wcat, C1u, 2048, 1024, 16);

  // lc = bf16(all_c @ Wlc^T) : M=65536, N=512 (256^2 tile, BK=32) -> grid 512
  k_latg<<<512, 512, 0, stream>>>(all_c, Wlc, num_word, lc);

  // lattice cell epilogue: one block per batch, one thread per hc
  k_epi<<<4096, 512, 0, stream>>>(lc, all_c, C1u, num_word,
      b_ii, b_hi, b_ig, b_hg, b_io, b_ho, b_lx, b_lc, outH, outC);
}